// Round 1
// baseline (722.249 us; speedup 1.0000x reference)
//
#include <hip/hip_runtime.h>
#include <stdint.h>
#include <math.h>

// Problem constants (B=2,S=2048 -> T=4096 tokens), D=1024, U=4096, E=8, K=2
#define TTOK 4096
#define DDIM 1024
#define UDIM 4096
#define NEXP 8

using float4v  = __attribute__((ext_vector_type(4))) float;
using short8   = __attribute__((ext_vector_type(8))) short;
using ushort4v = __attribute__((ext_vector_type(4))) unsigned short;
using ushort8  = __attribute__((ext_vector_type(8))) unsigned short;

__device__ __forceinline__ unsigned short f2bf(float f) {
  union { float f; unsigned u; } v; v.f = f;
  unsigned r = v.u + 0x7FFFu + ((v.u >> 16) & 1u);  // RNE
  return (unsigned short)(r >> 16);
}

__device__ __forceinline__ void load_lds16(const void* g, void* l) {
  __builtin_amdgcn_global_load_lds(
      (const __attribute__((address_space(1))) unsigned int*)g,
      (__attribute__((address_space(3))) unsigned int*)l, 16, 0, 0);
}

__device__ __forceinline__ ushort8 pack8(float4v a, float4v b) {
  ushort8 o;
  o[0]=f2bf(a[0]); o[1]=f2bf(a[1]); o[2]=f2bf(a[2]); o[3]=f2bf(a[3]);
  o[4]=f2bf(b[0]); o[5]=f2bf(b[1]); o[6]=f2bf(b[2]); o[7]=f2bf(b[3]);
  return o;
}

// ---------------- fp32 -> bf16 bulk convert ----------------
__global__ void cvt_f32_bf16(const float4v* __restrict__ src,
                             ushort4v* __restrict__ dst, int n4) {
  int stride = gridDim.x * blockDim.x;
  for (int i = blockIdx.x * blockDim.x + threadIdx.x; i < n4; i += stride) {
    float4v v = src[i];
    ushort4v o;
    o[0] = f2bf(v[0]); o[1] = f2bf(v[1]); o[2] = f2bf(v[2]); o[3] = f2bf(v[3]);
    dst[i] = o;
  }
}

// ---------------- router: logits, top-2, softmax, expert lists ----------------
// one wave (64) per token
__global__ void router_kernel(const float* __restrict__ x,
                              const float* __restrict__ wr,
                              int* __restrict__ counts, int* __restrict__ list,
                              float* __restrict__ wpair) {
  const int t = blockIdx.x;
  const int lane = threadIdx.x;
  float acc[NEXP];
#pragma unroll
  for (int e = 0; e < NEXP; e++) acc[e] = 0.0f;
  const float* xr = x + (size_t)t * DDIM;
  for (int d = lane; d < DDIM; d += 64) {
    float xv = xr[d];
#pragma unroll
    for (int e = 0; e < NEXP; e++) acc[e] += xv * wr[e * DDIM + d];
  }
#pragma unroll
  for (int e = 0; e < NEXP; e++) {
#pragma unroll
    for (int off = 32; off > 0; off >>= 1) acc[e] += __shfl_xor(acc[e], off, 64);
  }
  if (lane == 0) {
    int e0 = 0; float l0 = acc[0];
    for (int e = 1; e < NEXP; e++) if (acc[e] > l0) { l0 = acc[e]; e0 = e; }
    int e1 = -1; float l1 = -3.4e38f;
    for (int e = 0; e < NEXP; e++) if (e != e0 && acc[e] > l1) { l1 = acc[e]; e1 = e; }
    float s1 = expf(l1 - l0);             // l0 >= l1
    float inv = 1.0f / (1.0f + s1);
    int p0 = atomicAdd(&counts[e0], 1);
    list[e0 * TTOK + p0] = 2 * t;
    wpair[2 * t] = inv;                   // w0
    int p1 = atomicAdd(&counts[e1], 1);
    list[e1 * TTOK + p1] = 2 * t + 1;
    wpair[2 * t + 1] = s1 * inv;          // w1
  }
}

// ---------------- stage A: h[pair,u] = gelu(x[tok] . Wup[e][u] + bup[e][u]) ----------------
// grid (UDIM/128, 32, NEXP), block 256. m97-style 128x128x32 tile, bf16 MFMA.
template <bool SRCBF>
__global__ __launch_bounds__(256, 2) void stage_up_k(
    const void* __restrict__ xsrc, const void* __restrict__ wsrc,
    const float* __restrict__ bup, const int* __restrict__ counts,
    const int* __restrict__ list, unsigned short* __restrict__ h) {
  const int e = blockIdx.z, mt = blockIdx.y, nt = blockIdx.x;
  const int cnt = counts[e];
  if (mt * 128 >= cnt) return;
  const int rem = min(128, cnt - mt * 128);
  const int* lst = list + e * TTOK + mt * 128;

  __shared__ __align__(16) unsigned short As[128 * 32];
  __shared__ __align__(16) unsigned short Bs[128 * 32];

  const int tid = threadIdx.x;
  const int wave = tid >> 6, lane = tid & 63;
  const int srow = tid >> 2, cell = tid & 3;

  const int tok0 = lst[min(srow, rem - 1)] >> 1;
  const int tok1 = lst[min(srow + 64, rem - 1)] >> 1;

  constexpr int ELT = SRCBF ? 2 : 4;
  const char* xa0 = (const char*)xsrc + (size_t)tok0 * DDIM * ELT;
  const char* xa1 = (const char*)xsrc + (size_t)tok1 * DDIM * ELT;
  const char* wb0 = (const char*)wsrc + ((size_t)e * UDIM + nt * 128 + srow) * DDIM * ELT;
  const char* wb1 = wb0 + (size_t)64 * DDIM * ELT;

  char* Asb = (char*)As;
  char* Bsb = (char*)Bs;
  const int ld0 = srow * 64 + cell * 16;  // == tid*16 : wave-uniform base + lane*16
  const int ld1 = ld0 + 64 * 64;

  const int wm = wave >> 1, wn = wave & 1;
  const int lane15 = lane & 15, quad = lane >> 4;
  const int aoff = (wm * 64 + lane15) * 32 + quad * 8;
  const int boff = (wn * 64 + lane15) * 32 + quad * 8;

  float4v acc[4][4];
#pragma unroll
  for (int i = 0; i < 4; i++)
#pragma unroll
    for (int j = 0; j < 4; j++) acc[i][j] = (float4v){0.f, 0.f, 0.f, 0.f};

  for (int k0 = 0; k0 < DDIM; k0 += 32) {
    if constexpr (SRCBF) {
      const int kb = k0 * 2 + cell * 16;
      load_lds16(xa0 + kb, Asb + ld0);
      load_lds16(xa1 + kb, Asb + ld1);
      load_lds16(wb0 + kb, Bsb + ld0);
      load_lds16(wb1 + kb, Bsb + ld1);
    } else {
      const int kb = k0 * 4 + cell * 32;
      float4v a0 = *(const float4v*)(xa0 + kb), a1 = *(const float4v*)(xa0 + kb + 16);
      float4v a2 = *(const float4v*)(xa1 + kb), a3 = *(const float4v*)(xa1 + kb + 16);
      float4v b0 = *(const float4v*)(wb0 + kb), b1 = *(const float4v*)(wb0 + kb + 16);
      float4v b2 = *(const float4v*)(wb1 + kb), b3 = *(const float4v*)(wb1 + kb + 16);
      *(ushort8*)(Asb + ld0) = pack8(a0, a1);
      *(ushort8*)(Asb + ld1) = pack8(a2, a3);
      *(ushort8*)(Bsb + ld0) = pack8(b0, b1);
      *(ushort8*)(Bsb + ld1) = pack8(b2, b3);
    }
    __syncthreads();
    short8 af[4], bf[4];
#pragma unroll
    for (int mi = 0; mi < 4; mi++) af[mi] = *(const short8*)(As + aoff + mi * 512);
#pragma unroll
    for (int ni = 0; ni < 4; ni++) bf[ni] = *(const short8*)(Bs + boff + ni * 512);
#pragma unroll
    for (int mi = 0; mi < 4; mi++)
#pragma unroll
      for (int ni = 0; ni < 4; ni++)
        acc[mi][ni] = __builtin_amdgcn_mfma_f32_16x16x32_bf16(af[mi], bf[ni], acc[mi][ni], 0, 0, 0);
    __syncthreads();
  }

  // epilogue: +bias, exact gelu, store bf16 h rows scattered by pair id
  const int ucol0 = nt * 128 + wn * 64;
  float bias[4];
#pragma unroll
  for (int ni = 0; ni < 4; ni++) bias[ni] = bup[e * UDIM + ucol0 + ni * 16 + lane15];
#pragma unroll
  for (int mi = 0; mi < 4; mi++) {
#pragma unroll
    for (int r = 0; r < 4; r++) {
      const int mrow = wm * 64 + mi * 16 + quad * 4 + r;  // C/D: row=quad*4+reg
      if (mrow < rem) {
        const int pair = lst[mrow];
        unsigned short* hr = h + (size_t)pair * UDIM;
#pragma unroll
        for (int ni = 0; ni < 4; ni++) {
          float v = acc[mi][ni][r] + bias[ni];
          v = 0.5f * v * (1.0f + erff(v * 0.70710678118654752f));
          hr[ucol0 + ni * 16 + lane15] = f2bf(v);
        }
      }
    }
  }
}

// ---------------- stage B: out[tok] += w * (h[pair] . Wdown[e][d] + bdown[e][d]) ----------------
// grid (DDIM/128, 32, NEXP), block 256.
template <bool WBF>
__global__ __launch_bounds__(256, 2) void stage_down_k(
    const unsigned short* __restrict__ h, const void* __restrict__ wsrc,
    const float* __restrict__ bdn, const float* __restrict__ wpair,
    const int* __restrict__ counts, const int* __restrict__ list,
    float* __restrict__ out) {
  const int e = blockIdx.z, mt = blockIdx.y, nt = blockIdx.x;
  const int cnt = counts[e];
  if (mt * 128 >= cnt) return;
  const int rem = min(128, cnt - mt * 128);
  const int* lst = list + e * TTOK + mt * 128;

  __shared__ __align__(16) unsigned short As[128 * 32];
  __shared__ __align__(16) unsigned short Bs[128 * 32];

  const int tid = threadIdx.x;
  const int wave = tid >> 6, lane = tid & 63;
  const int srow = tid >> 2, cell = tid & 3;

  const int p0 = lst[min(srow, rem - 1)];
  const int p1 = lst[min(srow + 64, rem - 1)];
  const char* ha0 = (const char*)h + (size_t)p0 * UDIM * 2;
  const char* ha1 = (const char*)h + (size_t)p1 * UDIM * 2;
  constexpr int ELT = WBF ? 2 : 4;
  const char* wb0 = (const char*)wsrc + ((size_t)e * DDIM + nt * 128 + srow) * UDIM * ELT;
  const char* wb1 = wb0 + (size_t)64 * UDIM * ELT;

  char* Asb = (char*)As;
  char* Bsb = (char*)Bs;
  const int ld0 = srow * 64 + cell * 16;
  const int ld1 = ld0 + 64 * 64;

  const int wm = wave >> 1, wn = wave & 1;
  const int lane15 = lane & 15, quad = lane >> 4;
  const int aoff = (wm * 64 + lane15) * 32 + quad * 8;
  const int boff = (wn * 64 + lane15) * 32 + quad * 8;

  float4v acc[4][4];
#pragma unroll
  for (int i = 0; i < 4; i++)
#pragma unroll
    for (int j = 0; j < 4; j++) acc[i][j] = (float4v){0.f, 0.f, 0.f, 0.f};

  for (int k0 = 0; k0 < UDIM; k0 += 32) {
    {
      const int kb = k0 * 2 + cell * 16;
      load_lds16(ha0 + kb, Asb + ld0);
      load_lds16(ha1 + kb, Asb + ld1);
    }
    if constexpr (WBF) {
      const int kb = k0 * 2 + cell * 16;
      load_lds16(wb0 + kb, Bsb + ld0);
      load_lds16(wb1 + kb, Bsb + ld1);
    } else {
      const int kb = k0 * 4 + cell * 32;
      float4v b0 = *(const float4v*)(wb0 + kb), b1 = *(const float4v*)(wb0 + kb + 16);
      float4v b2 = *(const float4v*)(wb1 + kb), b3 = *(const float4v*)(wb1 + kb + 16);
      *(ushort8*)(Bsb + ld0) = pack8(b0, b1);
      *(ushort8*)(Bsb + ld1) = pack8(b2, b3);
    }
    __syncthreads();
    short8 af[4], bf[4];
#pragma unroll
    for (int mi = 0; mi < 4; mi++) af[mi] = *(const short8*)(As + aoff + mi * 512);
#pragma unroll
    for (int ni = 0; ni < 4; ni++) bf[ni] = *(const short8*)(Bs + boff + ni * 512);
#pragma unroll
    for (int mi = 0; mi < 4; mi++)
#pragma unroll
      for (int ni = 0; ni < 4; ni++)
        acc[mi][ni] = __builtin_amdgcn_mfma_f32_16x16x32_bf16(af[mi], bf[ni], acc[mi][ni], 0, 0, 0);
    __syncthreads();
  }

  const int dcol0 = nt * 128 + wn * 64;
  float bias[4];
#pragma unroll
  for (int ni = 0; ni < 4; ni++) bias[ni] = bdn[e * DDIM + dcol0 + ni * 16 + lane15];
#pragma unroll
  for (int mi = 0; mi < 4; mi++) {
#pragma unroll
    for (int r = 0; r < 4; r++) {
      const int mrow = wm * 64 + mi * 16 + quad * 4 + r;
      if (mrow < rem) {
        const int pair = lst[mrow];
        const int tok = pair >> 1;
        const float w = wpair[pair];
        float* orow = out + (size_t)tok * DDIM;
#pragma unroll
        for (int ni = 0; ni < 4; ni++) {
          float v = acc[mi][ni][r] + bias[ni];
          atomicAdd(&orow[dcol0 + ni * 16 + lane15], w * v);
        }
      }
    }
  }
}

extern "C" void kernel_launch(void* const* d_in, const int* in_sizes, int n_in,
                              void* d_out, int out_size, void* d_ws, size_t ws_size,
                              hipStream_t stream) {
  (void)in_sizes; (void)n_in; (void)out_size;
  const float* x        = (const float*)d_in[0];
  const float* w_router = (const float*)d_in[1];
  const float* w_up     = (const float*)d_in[2];
  const float* b_up     = (const float*)d_in[3];
  const float* w_down   = (const float*)d_in[4];
  const float* b_down   = (const float*)d_in[5];
  float* out = (float*)d_out;

  char* ws = (char*)d_ws;
  size_t off = 0;
  auto take = [&](size_t b) { size_t o = off; off = (off + b + 255) & ~(size_t)255; return o; };
  unsigned short* h = (unsigned short*)(ws + take((size_t)TTOK * 2 * UDIM * 2));  // 64 MiB
  int* counts       = (int*)(ws + take(NEXP * 4));
  int* list         = (int*)(ws + take((size_t)NEXP * TTOK * 4));
  float* wpair      = (float*)(ws + take((size_t)TTOK * 2 * 4));
  size_t xb_off  = take((size_t)TTOK * DDIM * 2);
  size_t wub_off = take((size_t)NEXP * UDIM * DDIM * 2);
  size_t wdb_off = take((size_t)NEXP * DDIM * UDIM * 2);
  const bool full = ws_size >= off;  // ~210 MB plan; else convert-in-staging fallback

  hipMemsetAsync(d_out, 0, (size_t)TTOK * DDIM * 4, stream);
  hipMemsetAsync(counts, 0, NEXP * 4, stream);

  router_kernel<<<TTOK, 64, 0, stream>>>(x, w_router, counts, list, wpair);

  if (full) {
    unsigned short* xb  = (unsigned short*)(ws + xb_off);
    unsigned short* wub = (unsigned short*)(ws + wub_off);
    unsigned short* wdb = (unsigned short*)(ws + wdb_off);
    cvt_f32_bf16<<<2048, 256, 0, stream>>>((const float4v*)x, (ushort4v*)xb, TTOK * DDIM / 4);
    cvt_f32_bf16<<<4096, 256, 0, stream>>>((const float4v*)w_up, (ushort4v*)wub, NEXP * UDIM * DDIM / 4);
    cvt_f32_bf16<<<4096, 256, 0, stream>>>((const float4v*)w_down, (ushort4v*)wdb, NEXP * DDIM * UDIM / 4);
    stage_up_k<true><<<dim3(UDIM / 128, 32, NEXP), 256, 0, stream>>>(xb, wub, b_up, counts, list, h);
    stage_down_k<true><<<dim3(DDIM / 128, 32, NEXP), 256, 0, stream>>>(h, wdb, b_down, wpair, counts, list, out);
  } else {
    stage_up_k<false><<<dim3(UDIM / 128, 32, NEXP), 256, 0, stream>>>(x, w_up, b_up, counts, list, h);
    stage_down_k<false><<<dim3(DDIM / 128, 32, NEXP), 256, 0, stream>>>(h, w_down, b_down, wpair, counts, list, out);
  }
}